// Round 7
// baseline (2622.010 us; speedup 1.0000x reference)
//
#include <hip/hip_runtime.h>

// ---------- types ----------
typedef short short8 __attribute__((ext_vector_type(8)));   // 8 bf16 in 4 VGPRs
typedef float f32x4 __attribute__((ext_vector_type(4)));    // MFMA accumulator

#define N_USERS 4096
#define T_STEPS 64
#define SKEP 768
#define HDIM 256
#define KROLE 64

// ---------- helpers ----------
__device__ __forceinline__ unsigned short f2bfs(float f) {
  unsigned int u = __builtin_bit_cast(unsigned int, f);
  u += 0x7fffu + ((u >> 16) & 1u);          // round-to-nearest-even
  return (unsigned short)(u >> 16);
}
__device__ __forceinline__ float bf2f(unsigned short b) {
  unsigned int u = ((unsigned int)b) << 16;
  return __builtin_bit_cast(float, u);
}
__device__ __forceinline__ short8 pack8(float4 a, float4 b) {
  short8 o;
  o[0] = (short)f2bfs(a.x); o[1] = (short)f2bfs(a.y);
  o[2] = (short)f2bfs(a.z); o[3] = (short)f2bfs(a.w);
  o[4] = (short)f2bfs(b.x); o[5] = (short)f2bfs(b.y);
  o[6] = (short)f2bfs(b.z); o[7] = (short)f2bfs(b.w);
  return o;
}
__device__ __forceinline__ float sigm(float x) { return 1.0f / (1.0f + __expf(-x)); }
__device__ __forceinline__ float tanh_(float x) { return 1.0f - 2.0f / (1.0f + __expf(2.0f * x)); }

// async global->LDS, 16B/lane, linear dest (wave-uniform base + lane*16)
__device__ __forceinline__ void gload16(const void* g, void* l) {
  __builtin_amdgcn_global_load_lds(
      (const __attribute__((address_space(1))) unsigned int*)g,
      (__attribute__((address_space(3))) unsigned int*)l, 16, 0, 0);
}

// ---------- k_prep: build wcatX (bigx B image), wfrag (lstm W frags), bias ----------
// gate-col c: gate gi=(c>>4)&3, unit u=((c>>6)<<4)|(c&15) -> orig row gi*256+u.
// wcatX image (Nt,kt): chunk i holds row r=i>>3, logical cl=(i&7)^(r&7) of W_ih.
// wfrag: per (w=c>>7, ks, nj=(c>>4)&7): 64 lanes x 8 el; lane lg*16+lr holds
//        W_hh[col = w*128+nj*16+lr][k = ks*32+lg*8 .. +8]  (contiguous 1KB/frag).
__global__ __launch_bounds__(256) void k_prep(
    const float* __restrict__ Wih, const float* __restrict__ Whh,
    const float* __restrict__ bih, const float* __restrict__ bhh,
    unsigned short* __restrict__ wcatX, unsigned short* __restrict__ wfrag,
    float* __restrict__ bias)
{
  const int c = blockIdx.x;
  const int gi = (c >> 4) & 3;
  const int u = ((c >> 6) << 4) | (c & 15);
  const int orig = gi * HDIM + u;
  const int tid = threadIdx.x;

  // wcatX (W_ih image for bigx B)
  const int NtX = c >> 7, rrX = c & 127;
  for (int kcol = tid; kcol < SKEP; kcol += 256) {
    int kt = kcol >> 6, kk = kcol & 63, cl = kk >> 3, e = kk & 7;
    int i = rrX * 8 + (cl ^ (rrX & 7));
    wcatX[(size_t)(NtX * 12 + kt) * 8192 + i * 8 + e] =
        f2bfs(Wih[(size_t)orig * SKEP + kcol]);
  }

  // wfrag (W_hh frags for lstm B): thread tid handles k=tid
  {
    const int w = c >> 7, nj = (c >> 4) & 7, lr = c & 15;
    const int k = tid;                      // 0..255
    const int ks = k >> 5, lg2 = (k >> 3) & 3, e = k & 7;
    wfrag[(size_t)((w * 8 + ks) * 8 + nj) * 512 + (lg2 * 16 + lr) * 8 + e] =
        f2bfs(Whh[(size_t)orig * HDIM + k]);
  }
  if (tid == 0) bias[c] = bih[orig] + bhh[orig];
}

// ---------- k_cast: hist fp32 -> pre-swizzled bf16 tile image (bigx A) ----------
// image chunk G: t=G/393216, Mtu=(G%393216)/12288, kt=(G%12288)>>10, i=G&1023;
// r=i>>3, cl=(i&7)^(r&7): holds hist[Mtu*128+r][t][kt*64+cl*8 .. +8].
__global__ __launch_bounds__(256) void k_cast(
    const float* __restrict__ hist, unsigned short* __restrict__ histb)
{
  int G = blockIdx.x * 1024 + threadIdx.x;
#pragma unroll
  for (int it = 0; it < 4; ++it, G += 256) {
    int t = G / 393216;
    int rem = G - t * 393216;
    int Mtu = rem / 12288;
    int rem2 = rem - Mtu * 12288;
    int kt = rem2 >> 10;
    int i = rem2 & 1023;
    int rr = i >> 3, pc = i & 7, cl = pc ^ (rr & 7);
    const float* src = hist +
        ((size_t)(Mtu * 128 + rr) * T_STEPS + t) * SKEP + kt * 64 + cl * 8;
    float4 a = *(const float4*)src, b = *(const float4*)(src + 4);
    *(short8*)(histb + (size_t)G * 8) = pack8(a, b);
  }
}

// ---------- k_bigx: X = hist_bf16 @ W_ih^T, both operands via global_load_lds ----------
// 256 thr (4 waves, 64x64 quadrant each, acc[4][4]), 64 KB LDS dbuf, 2 blk/CU.
// X layout (matches k_lstm): elem ((t*128+gg)*512 + w*64+lane)*64 + mi*32+nj_l*4+q.
__global__ __launch_bounds__(256, 2) void k_bigx(
    const unsigned short* __restrict__ histb,
    const unsigned short* __restrict__ wcatX,
    unsigned short* __restrict__ X)
{
  __shared__ __align__(16) unsigned char smem[65536];
  unsigned char* const A0 = smem;
  unsigned char* const B0 = smem + 16384;
  unsigned char* const A1 = smem + 32768;
  unsigned char* const B1 = smem + 49152;

  const int tid = threadIdx.x;
  const int lane = tid & 63;
  const int wid = tid >> 6;      // 0..3
  const int wr2 = wid >> 1;      // 0..1 (M half)
  const int wc2 = wid & 1;       // 0..1 (N half)
  const int lr = lane & 15;
  const int lg = lane >> 4;

  const int d = blockIdx.x;
  const int x = d & 7;
  const int Nt = (d >> 3) & 7;
  const int g = ((d >> 6) << 3) | x;          // 0..2047
  const int t = g >> 5;                       // 0..63
  const int Mtu = g & 31;                     // 0..31

  f32x4 acc[4][4];
#pragma unroll
  for (int mi = 0; mi < 4; ++mi)
#pragma unroll
    for (int nj = 0; nj < 4; ++nj) acc[mi][nj] = f32x4{0.f, 0.f, 0.f, 0.f};

  const unsigned short* imgA0 = histb + (size_t)((t * 32 + Mtu) * 12) * 8192;
  const unsigned short* imgB0 = wcatX + (size_t)(Nt * 12) * 8192;

  // prologue: stage kt=0 (A+B, 8 gloads)
#pragma unroll
  for (int ci = 0; ci < 4; ++ci) {
    gload16(imgA0 + (size_t)(ci * 256 + tid) * 8, A0 + ci * 4096 + wid * 1024);
    gload16(imgB0 + (size_t)(ci * 256 + tid) * 8, B0 + ci * 4096 + wid * 1024);
  }
  __syncthreads();

  for (int kt = 0; kt < 12; ++kt) {
    unsigned char* curA = (kt & 1) ? A1 : A0;
    unsigned char* curB = (kt & 1) ? B1 : B0;
    unsigned char* nxtA = (kt & 1) ? A0 : A1;
    unsigned char* nxtB = (kt & 1) ? B0 : B1;
    const int kn = kt + 1;

    if (kn < 12) {
      const unsigned short* iA = imgA0 + (size_t)kn * 8192;
      const unsigned short* iB = imgB0 + (size_t)kn * 8192;
#pragma unroll
      for (int ci = 0; ci < 4; ++ci) {
        gload16(iA + (size_t)(ci * 256 + tid) * 8, nxtA + ci * 4096 + wid * 1024);
        gload16(iB + (size_t)(ci * 256 + tid) * 8, nxtB + ci * 4096 + wid * 1024);
      }
    }

#pragma unroll
    for (int ks = 0; ks < 2; ++ks) {
      short8 av[4], bv[4];
#pragma unroll
      for (int mi = 0; mi < 4; ++mi) {
        int r = wr2 * 64 + mi * 16 + lr;
        int ph = (ks * 4 + lg) ^ (r & 7);
        av[mi] = *(const short8*)(curA + r * 128 + ph * 16);
      }
#pragma unroll
      for (int nj = 0; nj < 4; ++nj) {
        int r = wc2 * 64 + nj * 16 + lr;
        int ph = (ks * 4 + lg) ^ (r & 7);
        bv[nj] = *(const short8*)(curB + r * 128 + ph * 16);
      }
#pragma unroll
      for (int mi = 0; mi < 4; ++mi)
#pragma unroll
        for (int nj = 0; nj < 4; ++nj)
          acc[mi][nj] = __builtin_amdgcn_mfma_f32_16x16x32_bf16(av[mi], bv[nj], acc[mi][nj], 0, 0, 0);
    }
    __syncthreads();   // drains gload vmcnt + frag lgkm before swap
  }

  // epilogue: 4 x 32B stores into k_lstm-ordered X
#pragma unroll
  for (int p = 0; p < 2; ++p) {
    const int gg2 = Mtu * 4 + wr2 * 2 + p;
#pragma unroll
    for (int ml = 0; ml < 2; ++ml) {
      unsigned short tmp[16];
#pragma unroll
      for (int nj = 0; nj < 4; ++nj)
#pragma unroll
        for (int q = 0; q < 4; ++q)
          tmp[nj * 4 + q] = f2bfs(acc[p * 2 + ml][nj][q]);
      const size_t base =
          (((size_t)t * 128 + gg2) * 512 + Nt * 64 + lane) * 64 + ml * 32 + wc2 * 16;
      *(short8*)(X + base) = *(const short8*)(tmp);
      *(short8*)(X + base + 8) = *(const short8*)(tmp + 8);
    }
  }
}

// ---------- k_lstm: sync-free persistent; block owns 32 users x ALL 1024 cols ----------
// 128 blocks x 512 thr. h lives in 16 KB LDS (never leaves block). W_hh streamed
// from L2 every step via frag-major wfrag (1 KB contiguous per wave-load).
// Wave w owns cols w*128..+128 (units w*32..+32, all 4 gates). c/h in registers.
__global__ __launch_bounds__(512, 2) void k_lstm(
    const unsigned short* __restrict__ X,
    unsigned short* __restrict__ hfin,
    const unsigned short* __restrict__ wfrag,
    const float* __restrict__ bias,
    const int* __restrict__ lengths)
{
  __shared__ __align__(16) unsigned char hl[16384];  // h [32 users][256 units], XOR-swz

  const int tid = threadIdx.x;
  const int lane = tid & 63;
  const int w = tid >> 6;          // 0..7 (col block)
  const int lr = lane & 15, lg = lane >> 4;
  const int gg = blockIdx.x;       // 0..127
  const int n0 = gg * 32;

  float bs[8];
#pragma unroll
  for (int nj = 0; nj < 8; ++nj) bs[nj] = bias[w * 128 + nj * 16 + lr];
  int len8[2][4];
#pragma unroll
  for (int mi = 0; mi < 2; ++mi)
#pragma unroll
    for (int q = 0; q < 4; ++q)
      len8[mi][q] = lengths[n0 + mi * 16 + lg * 4 + q];

  float c16[2][2][4];
  unsigned short hp[2][2][4];
#pragma unroll
  for (int mi = 0; mi < 2; ++mi)
#pragma unroll
    for (int us = 0; us < 2; ++us)
#pragma unroll
      for (int q = 0; q < 4; ++q) { c16[mi][us][q] = 0.f; hp[mi][us][q] = 0; }

  for (int i = tid; i < 4096; i += 512) ((unsigned int*)hl)[i] = 0;

  const unsigned short* const wb = wfrag + (size_t)w * 32768;  // 8 ks x 8 nj x 512

#pragma unroll 1
  for (int t = 0; t < T_STEPS; ++t) {
    // X: 128 B/thread contiguous (consumed at epilogue; overlaps GEMM)
    const unsigned short* xp = X + (((size_t)t * 128 + gg) * 512 + tid) * 64;
    short8 xv[8];
#pragma unroll
    for (int j = 0; j < 8; ++j) xv[j] = *(const short8*)(xp + j * 8);

    __syncthreads();   // prev epilogue's hl writes visible (t=0: zero-init)

    f32x4 acc[2][8];
#pragma unroll
    for (int mi = 0; mi < 2; ++mi)
#pragma unroll
      for (int nj = 0; nj < 8; ++nj) acc[mi][nj] = f32x4{0.f, 0.f, 0.f, 0.f};

    short8 bvA[8], bvB[8];
#pragma unroll
    for (int nj = 0; nj < 8; ++nj)
      bvA[nj] = *(const short8*)(wb + (size_t)nj * 512 + lane * 8);

#pragma unroll
    for (int ks = 0; ks < 8; ++ks) {
      const short8* cur = (ks & 1) ? bvB : bvA;
      short8* nxt = (ks & 1) ? bvA : bvB;
      if (ks < 7) {
#pragma unroll
        for (int nj = 0; nj < 8; ++nj)
          nxt[nj] = *(const short8*)(wb + (size_t)((ks + 1) * 8 + nj) * 512 + lane * 8);
      }
      const int ch = ks * 4 + lg;
      short8 av0 = *(const short8*)(hl + lr * 512 + ((ch ^ (lr & 7)) << 4));
      short8 av1 = *(const short8*)(hl + (16 + lr) * 512 + ((ch ^ (lr & 7)) << 4));
#pragma unroll
      for (int nj = 0; nj < 8; ++nj) {
        acc[0][nj] = __builtin_amdgcn_mfma_f32_16x16x32_bf16(av0, cur[nj], acc[0][nj], 0, 0, 0);
        acc[1][nj] = __builtin_amdgcn_mfma_f32_16x16x32_bf16(av1, cur[nj], acc[1][nj], 0, 0, 0);
      }
    }
    __syncthreads();   // hl reads done before overwrite

    // ---- cell update; h -> LDS (unit = w*32 + us*16 + lr, gate = nj&3) ----
#pragma unroll
    for (int mi = 0; mi < 2; ++mi) {
#pragma unroll
      for (int q = 0; q < 4; ++q) {
        const int row = mi * 16 + lg * 4 + q;     // local user
        const bool act = (t < len8[mi][q]);
#pragma unroll
        for (int us = 0; us < 2; ++us) {
          const int i0 = mi * 32 + us * 16;       // X idx base: + gi2*4 + q
          float gi_ = sigm(acc[mi][us * 4 + 0][q] + bf2f((unsigned short)xv[(i0 + q) >> 3][(i0 + q) & 7]) + bs[us * 4 + 0]);
          float gf_ = sigm(acc[mi][us * 4 + 1][q] + bf2f((unsigned short)xv[(i0 + 4 + q) >> 3][(i0 + 4 + q) & 7]) + bs[us * 4 + 1]);
          float gg_ = tanh_(acc[mi][us * 4 + 2][q] + bf2f((unsigned short)xv[(i0 + 8 + q) >> 3][(i0 + 8 + q) & 7]) + bs[us * 4 + 2]);
          float go_ = sigm(acc[mi][us * 4 + 3][q] + bf2f((unsigned short)xv[(i0 + 12 + q) >> 3][(i0 + 12 + q) & 7]) + bs[us * 4 + 3]);
          if (act) {
            float cn = gf_ * c16[mi][us][q] + gi_ * gg_;
            c16[mi][us][q] = cn;
            hp[mi][us][q] = f2bfs(go_ * tanh_(cn));
          }
          const int uc = w * 4 + us * 2 + (lr >> 3);   // unit>>3
          *(unsigned short*)(hl + row * 512 + ((uc ^ (row & 7)) << 4) + (lr & 7) * 2) =
              hp[mi][us][q];
        }
      }
    }
  }

  // final h -> global [user][unit]
#pragma unroll
  for (int mi = 0; mi < 2; ++mi)
#pragma unroll
    for (int q = 0; q < 4; ++q)
#pragma unroll
      for (int us = 0; us < 2; ++us)
        hfin[(size_t)(n0 + mi * 16 + lg * 4 + q) * HDIM + w * 32 + us * 16 + lr] =
            hp[mi][us][q];
}

// ---------- Phase C1: s[n] = dot(cc[cid[n]], uv[n]) / sqrt(H) ----------
__global__ __launch_bounds__(256) void k_scores(
    const float* __restrict__ uv, const float* __restrict__ cc,
    const int* __restrict__ cid, float* __restrict__ s)
{
  int n = blockIdx.x * 4 + (threadIdx.x >> 6);
  int lane = threadIdx.x & 63;
  float4 a = *(const float4*)(uv + (size_t)n * HDIM + lane * 4);
  float4 b = *(const float4*)(cc + (size_t)cid[n] * HDIM + lane * 4);
  float dd = a.x * b.x + a.y * b.y + a.z * b.z + a.w * b.w;
  for (int off = 32; off; off >>= 1) dd += __shfl_down(dd, off);
  if (lane == 0) s[n] = dd * 0.0625f;   // 1/sqrt(256)
}

// ---------- Phase C2: segment softmax + role_senti ----------
__global__ __launch_bounds__(256) void k_role(
    const float* __restrict__ s, const int* __restrict__ cid,
    const unsigned short* __restrict__ hn, float* __restrict__ rs)
{
  __shared__ float sv[N_USERS];
  __shared__ int cv[N_USERS];
  __shared__ float red[256];
  const int k = blockIdx.x, tid = threadIdx.x;
  for (int i = tid; i < N_USERS; i += 256) { sv[i] = s[i]; cv[i] = cid[i]; }
  __syncthreads();
  float m = -3.4e38f;
  for (int i = tid; i < N_USERS; i += 256) if (cv[i] == k) m = fmaxf(m, sv[i]);
  red[tid] = m; __syncthreads();
  for (int st = 128; st; st >>= 1) { if (tid < st) red[tid] = fmaxf(red[tid], red[tid + st]); __syncthreads(); }
  const float smax = red[0];
  __syncthreads();
  float sum = 0.f;
  for (int i = tid; i < N_USERS; i += 256)
    if (cv[i] == k) { float e = __expf(sv[i] - smax); sv[i] = e; sum += e; }
  red[tid] = sum; __syncthreads();
  for (int st = 128; st; st >>= 1) { if (tid < st) red[tid] += red[tid + st]; __syncthreads(); }
  const float den = red[0];
  __syncthreads();
  float a = 0.f;
  for (int i = 0; i < N_USERS; ++i)
    if (cv[i] == k) a += sv[i] * bf2f(hn[(size_t)i * HDIM + tid]);
  rs[(size_t)k * HDIM + tid] = a / den;
}

// ---------- Phase D1: per-head MHA over roles ----------
__global__ __launch_bounds__(256) void k_mha(
    const float* __restrict__ rs,
    const float* __restrict__ Wq, const float* __restrict__ bq,
    const float* __restrict__ Wk, const float* __restrict__ bk,
    const float* __restrict__ Wv, const float* __restrict__ bv,
    float* __restrict__ attout)
{
  __shared__ float q[64][32], kk[64][32], v[64][32];
  __shared__ float att[64][64];
  const int h = blockIdx.x, tid = threadIdx.x;
  for (int idx = tid; idx < 2048; idx += 256) {
    int r = idx >> 5, dd2 = idx & 31;
    int wrow = h * 32 + dd2;
    float aq = bq[wrow], ak = bk[wrow], av = bv[wrow];
    const float* x = rs + (size_t)r * HDIM;
    const float* wq = Wq + (size_t)wrow * HDIM;
    const float* wk = Wk + (size_t)wrow * HDIM;
    const float* wv = Wv + (size_t)wrow * HDIM;
    for (int j = 0; j < HDIM; ++j) {
      float xv = x[j];
      aq += xv * wq[j]; ak += xv * wk[j]; av += xv * wv[j];
    }
    q[r][dd2] = aq; kk[r][dd2] = ak; v[r][dd2] = av;
  }
  __syncthreads();
  for (int idx = tid; idx < 4096; idx += 256) {
    int qr = idx >> 6, kr = idx & 63;
    float sc = 0.f;
    for (int dd2 = 0; dd2 < 32; ++dd2) sc += q[qr][dd2] * kk[kr][dd2];
    att[qr][kr] = sc * 0.17677669529663687f;   // 1/sqrt(32)
  }
  __syncthreads();
  if (tid < 64) {
    float m = -3.4e38f;
    for (int j = 0; j < 64; ++j) m = fmaxf(m, att[tid][j]);
    float sum = 0.f;
    for (int j = 0; j < 64; ++j) { float e = __expf(att[tid][j] - m); att[tid][j] = e; sum += e; }
    float inv = 1.f / sum;
    for (int j = 0; j < 64; ++j) att[tid][j] *= inv;
  }
  __syncthreads();
  for (int idx = tid; idx < 2048; idx += 256) {
    int r = idx >> 5, dd2 = idx & 31;
    float o = 0.f;
    for (int kr = 0; kr < 64; ++kr) o += att[r][kr] * v[kr][dd2];
    attout[(size_t)r * HDIM + h * 32 + dd2] = o;
  }
}

// ---------- Phase D2: mean over roles + Wo projection ----------
__global__ __launch_bounds__(256) void k_out(
    const float* __restrict__ attout, const float* __restrict__ Wo,
    const float* __restrict__ bo, float* __restrict__ out)
{
  __shared__ float m_s[256];
  const int tid = threadIdx.x;
  float mm = 0.f;
  for (int r = 0; r < 64; ++r) mm += attout[(size_t)r * HDIM + tid];
  m_s[tid] = mm * (1.0f / 64.0f);
  __syncthreads();
  float a = bo[tid];
  for (int j = 0; j < HDIM; ++j) a += m_s[j] * Wo[(size_t)tid * HDIM + j];
  out[tid] = a;
}

extern "C" void kernel_launch(void* const* d_in, const int* in_sizes, int n_in,
                              void* d_out, int out_size, void* d_ws, size_t ws_size,
                              hipStream_t stream) {
  const float* hist = (const float*)d_in[0];
  const float* uv   = (const float*)d_in[1];
  const float* cc   = (const float*)d_in[2];
  const float* Wih  = (const float*)d_in[3];
  const float* Whh  = (const float*)d_in[4];
  const float* bih  = (const float*)d_in[5];
  const float* bhh  = (const float*)d_in[6];
  const float* Wq   = (const float*)d_in[7];
  const float* bq   = (const float*)d_in[8];
  const float* Wk   = (const float*)d_in[9];
  const float* bk   = (const float*)d_in[10];
  const float* Wv   = (const float*)d_in[11];
  const float* bv   = (const float*)d_in[12];
  const float* Wo   = (const float*)d_in[13];
  const float* bo   = (const float*)d_in[14];
  const int* lengths = (const int*)d_in[15];
  const int* cid     = (const int*)d_in[16];
  float* out = (float*)d_out;

  unsigned char* ws = (unsigned char*)d_ws;
  unsigned short* hfin  = (unsigned short*)(ws);                       // 2 MB
  float* bias   = (float*)(ws + 0x200000);                             // 4 KB
  float* sbuf   = (float*)(ws + 0x202000);                             // 16 KB
  float* rs     = (float*)(ws + 0x206000);                             // 64 KB
  float* attout = (float*)(ws + 0x216000);                             // 64 KB
  unsigned short* wfrag = (unsigned short*)(ws + 0x230000);            // 512 KB
  unsigned short* wcatX = (unsigned short*)(ws + 0x300000);            // 1.5 MB
  unsigned short* Xbuf  = (unsigned short*)(ws + (16ull << 20));       // 512 MB
  unsigned short* histb = (unsigned short*)(ws + (544ull << 20));      // 403 MB
  const size_t need = (544ull << 20) + 25165824ull * 16;
  if (ws_size < need) return;

  k_prep<<<1024, 256, 0, stream>>>(Wih, Whh, bih, bhh, wcatX, wfrag, bias);
  k_cast<<<24576, 256, 0, stream>>>(hist, histb);
  k_bigx<<<16384, 256, 0, stream>>>(histb, wcatX, Xbuf);
  k_lstm<<<128, 512, 0, stream>>>(Xbuf, hfin, wfrag, bias, lengths);

  k_scores<<<1024, 256, 0, stream>>>(uv, cc, cid, sbuf);
  k_role<<<64, 256, 0, stream>>>(sbuf, cid, hfin, rs);
  k_mha<<<8, 256, 0, stream>>>(rs, Wq, bq, Wk, bk, Wv, bv, attout);
  k_out<<<1, 256, 0, stream>>>(attout, Wo, bo, out);
}

// Round 8
// 1599.626 us; speedup vs baseline: 1.6391x; 1.6391x over previous
//
#include <hip/hip_runtime.h>

// ---------- types ----------
typedef short short8 __attribute__((ext_vector_type(8)));   // 8 bf16 in 4 VGPRs
typedef float f32x4 __attribute__((ext_vector_type(4)));    // MFMA accumulator

#define N_USERS 4096
#define T_STEPS 64
#define SKEP 768
#define HDIM 256
#define KROLE 64

// ---------- helpers ----------
__device__ __forceinline__ unsigned short f2bfs(float f) {
  unsigned int u = __builtin_bit_cast(unsigned int, f);
  u += 0x7fffu + ((u >> 16) & 1u);          // round-to-nearest-even
  return (unsigned short)(u >> 16);
}
__device__ __forceinline__ float bf2f(unsigned short b) {
  unsigned int u = ((unsigned int)b) << 16;
  return __builtin_bit_cast(float, u);
}
__device__ __forceinline__ short8 pack8(float4 a, float4 b) {
  short8 o;
  o[0] = (short)f2bfs(a.x); o[1] = (short)f2bfs(a.y);
  o[2] = (short)f2bfs(a.z); o[3] = (short)f2bfs(a.w);
  o[4] = (short)f2bfs(b.x); o[5] = (short)f2bfs(b.y);
  o[6] = (short)f2bfs(b.z); o[7] = (short)f2bfs(b.w);
  return o;
}
__device__ __forceinline__ float sigm(float x) { return 1.0f / (1.0f + __expf(-x)); }
__device__ __forceinline__ float tanh_(float x) { return 1.0f - 2.0f / (1.0f + __expf(2.0f * x)); }

// async global->LDS, 16B/lane, linear dest (wave-uniform base + lane*16)
__device__ __forceinline__ void gload16(const void* g, void* l) {
  __builtin_amdgcn_global_load_lds(
      (const __attribute__((address_space(1))) unsigned int*)g,
      (__attribute__((address_space(3))) unsigned int*)l, 16, 0, 0);
}

// coherence-point (sc0 sc1) 8B store: visible device-wide after vmcnt(0)
__device__ __forceinline__ void store_u64_coh(unsigned short* p, unsigned long long v) {
  asm volatile("global_store_dwordx2 %0, %1, off sc0 sc1" : : "v"(p), "v"(v) : "memory");
}

// ---------- k_prep: wcat (gate-permuted [Whh|Wih]), wcatX (bigx B image), bias ----------
// gate-col c: gate gi=(c>>4)&3, unit u=((c>>6)<<4)|(c&15) -> orig row gi*256+u.
// wcatX image (Nt,kt): chunk i (0..1023) holds row r=i>>3, logical cl=(i&7)^(r&7) of W_ih.
__global__ __launch_bounds__(256) void k_prep(
    const float* __restrict__ Wih, const float* __restrict__ Whh,
    const float* __restrict__ bih, const float* __restrict__ bhh,
    unsigned short* __restrict__ wcat, unsigned short* __restrict__ wcatX,
    float* __restrict__ bias)
{
  int c = blockIdx.x;
  int gi = (c >> 4) & 3;
  int u = ((c >> 6) << 4) | (c & 15);
  int orig = gi * HDIM + u;
  for (int k = threadIdx.x; k < 1024; k += 256) {
    float w = (k < HDIM) ? Whh[(size_t)orig * HDIM + k]
                         : Wih[(size_t)orig * SKEP + (k - HDIM)];
    wcat[(size_t)c * 1024 + k] = f2bfs(w);
  }
  const int NtX = c >> 7, rrX = c & 127;
  for (int kcol = threadIdx.x; kcol < SKEP; kcol += 256) {
    int kt = kcol >> 6, kk = kcol & 63, cl = kk >> 3, e = kk & 7;
    int i = rrX * 8 + (cl ^ (rrX & 7));
    wcatX[(size_t)(NtX * 12 + kt) * 8192 + i * 8 + e] =
        f2bfs(Wih[(size_t)orig * SKEP + kcol]);
  }
  if (threadIdx.x == 0) bias[c] = bih[orig] + bhh[orig];
}

// ---------- k_bigx (r5 structure, measured 810us): X = hist @ W_ih^T ----------
// 512 thr / 8 waves / acc[2][4]; A reg-staged from fp32 hist, B via gload_lds
// from pre-swizzled wcatX. NEW epilogue: each thread's 32 accs are exactly one
// k_lstm thread's contiguous 64B chunk:
//   slab = t*256 + (Mtu*4+wr)*2 + (Nt>>2); tidc = ((Nt*2+wc)&7)*64 + lg*16+lr;
//   X[(slab*512 + tidc)*32 + mi*16 + nj*4 + q]
__global__ __launch_bounds__(512) void k_bigx(
    const float* __restrict__ hist,
    const unsigned short* __restrict__ wcatX,
    unsigned short* __restrict__ X)
{
  __shared__ __align__(16) unsigned char smem[65536];
  unsigned char* const A0 = smem;
  unsigned char* const B0 = smem + 16384;
  unsigned char* const A1 = smem + 32768;
  unsigned char* const B1 = smem + 49152;

  const int tid = threadIdx.x;
  const int lane = tid & 63;
  const int wid = tid >> 6;
  const int wr = wid >> 1;       // 0..3
  const int wc = wid & 1;        // 0..1
  const int lr = lane & 15;
  const int lg = lane >> 4;

  const int d = blockIdx.x;
  const int x = d & 7;
  const int Nt = (d >> 3) & 7;
  const int g = ((d >> 6) << 3) | x;          // 0..2047
  const int t = g >> 5;                       // 0..63
  const int Mtu = g & 31;                     // 0..31
  const int n0 = Mtu * 128;

  f32x4 acc[2][4];
#pragma unroll
  for (int mi = 0; mi < 2; ++mi)
#pragma unroll
    for (int nj = 0; nj < 4; ++nj) acc[mi][nj] = f32x4{0.f, 0.f, 0.f, 0.f};

  const int rr = tid >> 3;                    // 0..63
  const int cl = (tid & 7) ^ (rr & 7);        // XOR swizzle chunk (A side)
  const size_t hA0 = ((size_t)(n0 + rr) * T_STEPS + t) * SKEP + (size_t)cl * 8;
  const size_t hA1 = ((size_t)(n0 + rr + 64) * T_STEPS + t) * SKEP + (size_t)cl * 8;
  const int dst0 = tid * 16, dst1 = tid * 16 + 8192;

  // prologue: stage kt=0 (B async via gload_lds, A via regs)
  {
    const unsigned short* img = wcatX + (size_t)(Nt * 12) * 8192;
    gload16(img + (size_t)tid * 8, B0 + wid * 1024);
    gload16(img + (size_t)(tid + 512) * 8, B0 + 8192 + wid * 1024);
    const float* p0 = hist + hA0;
    const float* p1 = hist + hA1;
    float4 f00 = *(const float4*)p0, f01 = *(const float4*)(p0 + 4);
    float4 f10 = *(const float4*)p1, f11 = *(const float4*)(p1 + 4);
    *(short8*)(A0 + dst0) = pack8(f00, f01);
    *(short8*)(A0 + dst1) = pack8(f10, f11);
  }
  __syncthreads();

  for (int kt = 0; kt < 12; ++kt) {
    unsigned char* curA = (kt & 1) ? A1 : A0;
    unsigned char* curB = (kt & 1) ? B1 : B0;
    unsigned char* nxtA = (kt & 1) ? A0 : A1;
    unsigned char* nxtB = (kt & 1) ? B0 : B1;
    const int kn = kt + 1;
    const bool have = (kn < 12);

    float4 f00, f01, f10, f11;
    if (have) {
      const unsigned short* img = wcatX + (size_t)(Nt * 12 + kn) * 8192;
      gload16(img + (size_t)tid * 8, nxtB + wid * 1024);
      gload16(img + (size_t)(tid + 512) * 8, nxtB + 8192 + wid * 1024);
      const float* p0 = hist + hA0 + (size_t)kn * 64;
      const float* p1 = hist + hA1 + (size_t)kn * 64;
      f00 = *(const float4*)p0; f01 = *(const float4*)(p0 + 4);
      f10 = *(const float4*)p1; f11 = *(const float4*)(p1 + 4);
    }

#pragma unroll
    for (int ks = 0; ks < 2; ++ks) {
      short8 av[2], bv[4];
#pragma unroll
      for (int mi = 0; mi < 2; ++mi) {
        int r = wr * 32 + mi * 16 + lr;
        int ph = (ks * 4 + lg) ^ (r & 7);
        av[mi] = *(const short8*)(curA + r * 128 + ph * 16);
      }
#pragma unroll
      for (int nj = 0; nj < 4; ++nj) {
        int r = wc * 64 + nj * 16 + lr;
        int ph = (ks * 4 + lg) ^ (r & 7);
        bv[nj] = *(const short8*)(curB + r * 128 + ph * 16);
      }
#pragma unroll
      for (int mi = 0; mi < 2; ++mi)
#pragma unroll
        for (int nj = 0; nj < 4; ++nj)
          acc[mi][nj] = __builtin_amdgcn_mfma_f32_16x16x32_bf16(av[mi], bv[nj], acc[mi][nj], 0, 0, 0);
    }

    if (have) {
      *(short8*)(nxtA + dst0) = pack8(f00, f01);
      *(short8*)(nxtA + dst1) = pack8(f10, f11);
    }
    __syncthreads();   // drains gload vmcnt + frag lgkm before swap
  }

  // epilogue: one contiguous 64B chunk per thread (k_lstm layout)
  unsigned short tmp[32];
#pragma unroll
  for (int mi = 0; mi < 2; ++mi)
#pragma unroll
    for (int nj = 0; nj < 4; ++nj)
#pragma unroll
      for (int q = 0; q < 4; ++q)
        tmp[mi * 16 + nj * 4 + q] = f2bfs(acc[mi][nj][q]);
  const int slab = t * 256 + (Mtu * 4 + wr) * 2 + (Nt >> 2);
  const int tidc = ((Nt * 2 + wc) & 7) * 64 + lg * 16 + lr;
  const size_t base = ((size_t)slab * 512 + tidc) * 32;
#pragma unroll
  for (int j2 = 0; j2 < 4; ++j2)
    *(short8*)(X + base + j2 * 8) = *(const short8*)(tmp + j2 * 8);
}

// ---------- k_lstm: pair-split persistent, W_hh in registers (r6 design, cap fixed) ----------
// 256 blocks: b = gg*2 + half; block owns users gg*32..+32 x gate-cols
// half*512..+512 (units half*128..+128). Breg = 128 VGPR held whole kernel
// (launch_bounds(512) -> 256-VGPR budget, 1 block/CU). h full-K in 16KB LDS;
// partner half exchanged via 8KB sc1 stores + relaxed-agent loads.
__global__ __launch_bounds__(512) void k_lstm(
    const unsigned short* __restrict__ X,
    unsigned short* __restrict__ hfin,
    unsigned short* __restrict__ hx0,
    unsigned short* __restrict__ hx1,
    const unsigned short* __restrict__ wcat,
    const float* __restrict__ bias,
    const int* __restrict__ lengths,
    unsigned int* __restrict__ ctr)
{
  __shared__ __align__(16) unsigned char hl[16384];   // h [32 users][256 k] swizzled

  const int tid = threadIdx.x;
  const int lane = tid & 63;
  const int w = tid >> 6;          // 0..7
  const int lr = lane & 15, lg = lane >> 4;
  const int b = blockIdx.x;
  const int gg = b >> 1, half = b & 1;
  const int n0 = gg * 32;
  const int pb = b ^ 1;
  unsigned int* const cme = ctr + b * 16;
  unsigned int* const cpa = ctr + pb * 16;

  // ---- W_hh fragments into registers (held entire kernel) ----
  short8 Breg[32];
#pragma unroll
  for (int nj = 0; nj < 4; ++nj) {
    const unsigned short* wp =
        wcat + (size_t)(half * 512 + w * 64 + nj * 16 + lr) * 1024 + lg * 8;
#pragma unroll
    for (int ks = 0; ks < 8; ++ks)
      Breg[nj * 8 + ks] = *(const short8*)(wp + ks * 32);
  }

  float bs[4];
#pragma unroll
  for (int nj = 0; nj < 4; ++nj)
    bs[nj] = bias[half * 512 + w * 64 + nj * 16 + lr];
  int len[2][4];
#pragma unroll
  for (int mi = 0; mi < 2; ++mi)
#pragma unroll
    for (int q = 0; q < 4; ++q)
      len[mi][q] = lengths[n0 + mi * 16 + lg * 4 + q];

  const int unitg = half * 128 + w * 16 + lr;   // this thread's unit (0..255)
  const int uchunk = unitg >> 3;
  const int ulow = (unitg & 7) * 2;

  for (int i = tid; i < 4096; i += 512) ((unsigned int*)hl)[i] = 0;
  float c8[2][4] = {{0.f, 0.f, 0.f, 0.f}, {0.f, 0.f, 0.f, 0.f}};
  unsigned short hp8[2][4] = {{0, 0, 0, 0}, {0, 0, 0, 0}};
  __syncthreads();

#pragma unroll 1
  for (int t = 0; t < T_STEPS; ++t) {
    // X: one contiguous 64B read/thread (issued before the spin)
    const unsigned short* xp = X + (((size_t)t * 256 + b) * 512 + tid) * 32;
    const short8 xv0 = *(const short8*)(xp);
    const short8 xv1 = *(const short8*)(xp + 8);
    const short8 xv2 = *(const short8*)(xp + 16);
    const short8 xv3 = *(const short8*)(xp + 24);

    if (t > 0) {
      if (tid == 0) {
        while (__hip_atomic_load(cpa, __ATOMIC_RELAXED, __HIP_MEMORY_SCOPE_AGENT)
               < (unsigned)t)
          __builtin_amdgcn_s_sleep(1);
      }
      __syncthreads();
      // scatter partner half (h_{t-1} from hx[(t-1)&1]) into h_lds
      const unsigned long long* hs = (const unsigned long long*)
          (((t & 1) ? hx0 : hx1) + (size_t)pb * 4096);
      unsigned long long a0 = __hip_atomic_load(hs + tid * 2,
                                  __ATOMIC_RELAXED, __HIP_MEMORY_SCOPE_AGENT);
      unsigned long long a1 = __hip_atomic_load(hs + tid * 2 + 1,
                                  __ATOMIC_RELAXED, __HIP_MEMORY_SCOPE_AGENT);
      const int ku = (1 - half) * 128 + (tid >> 2);
      const int kc = ku >> 3, kl = (ku & 7) * 2;
      const int ub = (tid & 3) * 8;
#pragma unroll
      for (int j = 0; j < 8; ++j) {
        unsigned short hv = (unsigned short)
            ((j < 4) ? (a0 >> (j * 16)) : (a1 >> ((j - 4) * 16)));
        int us = ub + j;
        *(unsigned short*)(hl + us * 512 + ((kc ^ (us & 7)) << 4) + kl) = hv;
      }
      __syncthreads();
    }

    // ---- GEMM: gates = h @ W_hh^T (W in regs, h frags from LDS) ----
    f32x4 acc[2][4];
#pragma unroll
    for (int mi = 0; mi < 2; ++mi)
#pragma unroll
      for (int nj = 0; nj < 4; ++nj) acc[mi][nj] = f32x4{0.f, 0.f, 0.f, 0.f};

#pragma unroll
    for (int ks = 0; ks < 8; ++ks) {
      const int ch = ks * 4 + lg;
      short8 av0 = *(const short8*)(hl + lr * 512 + ((ch ^ (lr & 7)) << 4));
      short8 av1 = *(const short8*)(hl + (16 + lr) * 512 + ((ch ^ (lr & 7)) << 4));
#pragma unroll
      for (int nj = 0; nj < 4; ++nj) {
        acc[0][nj] = __builtin_amdgcn_mfma_f32_16x16x32_bf16(av0, Breg[nj * 8 + ks], acc[0][nj], 0, 0, 0);
        acc[1][nj] = __builtin_amdgcn_mfma_f32_16x16x32_bf16(av1, Breg[nj * 8 + ks], acc[1][nj], 0, 0, 0);
      }
    }
    __syncthreads();   // all frag reads done before h_lds overwrite

    // ---- cell update + h publication ----
    unsigned short* hxo = ((t & 1) ? hx1 : hx0) + (size_t)b * 4096;
#pragma unroll
    for (int mi = 0; mi < 2; ++mi) {
      const short8 xa = (mi == 0) ? xv0 : xv2;
      const short8 xb = (mi == 0) ? xv1 : xv3;
#pragma unroll
      for (int q = 0; q < 4; ++q) {
        float gi_ = sigm(acc[mi][0][q] + bf2f((unsigned short)xa[q])     + bs[0]);
        float gf_ = sigm(acc[mi][1][q] + bf2f((unsigned short)xa[4 + q]) + bs[1]);
        float gg_ = tanh_(acc[mi][2][q] + bf2f((unsigned short)xb[q])    + bs[2]);
        float go_ = sigm(acc[mi][3][q] + bf2f((unsigned short)xb[4 + q]) + bs[3]);
        if (t < len[mi][q]) {
          float cn = gf_ * c8[mi][q] + gi_ * gg_;
          c8[mi][q] = cn;
          hp8[mi][q] = f2bfs(go_ * tanh_(cn));
        }
        int us = mi * 16 + lg * 4 + q;
        *(unsigned short*)(hl + us * 512 + ((uchunk ^ (us & 7)) << 4) + ulow) = hp8[mi][q];
      }
      unsigned long long pk =
          (unsigned long long)hp8[mi][0] | ((unsigned long long)hp8[mi][1] << 16) |
          ((unsigned long long)hp8[mi][2] << 32) | ((unsigned long long)hp8[mi][3] << 48);
      store_u64_coh(hxo + (w * 16 + lr) * 32 + mi * 16 + lg * 4, pk);
    }

    asm volatile("s_waitcnt vmcnt(0)" ::: "memory");  // hx stores at coherence point
    __syncthreads();
    if (t < T_STEPS - 1 && tid == 0)
      __hip_atomic_fetch_add(cme, 1u, __ATOMIC_RELAXED, __HIP_MEMORY_SCOPE_AGENT);
  }

  // final h -> global [user][unit]
#pragma unroll
  for (int mi = 0; mi < 2; ++mi)
#pragma unroll
    for (int q = 0; q < 4; ++q)
      hfin[(size_t)(n0 + mi * 16 + lg * 4 + q) * HDIM + unitg] = hp8[mi][q];
}

// ---------- Phase C1: s[n] = dot(cc[cid[n]], uv[n]) / sqrt(H) ----------
__global__ __launch_bounds__(256) void k_scores(
    const float* __restrict__ uv, const float* __restrict__ cc,
    const int* __restrict__ cid, float* __restrict__ s)
{
  int n = blockIdx.x * 4 + (threadIdx.x >> 6);
  int lane = threadIdx.x & 63;
  float4 a = *(const float4*)(uv + (size_t)n * HDIM + lane * 4);
  float4 b = *(const float4*)(cc + (size_t)cid[n] * HDIM + lane * 4);
  float dd = a.x * b.x + a.y * b.y + a.z * b.z + a.w * b.w;
  for (int off = 32; off; off >>= 1) dd += __shfl_down(dd, off);
  if (lane == 0) s[n] = dd * 0.0625f;   // 1/sqrt(256)
}

// ---------- Phase C2: segment softmax + role_senti ----------
__global__ __launch_bounds__(256) void k_role(
    const float* __restrict__ s, const int* __restrict__ cid,
    const unsigned short* __restrict__ hn, float* __restrict__ rs)
{
  __shared__ float sv[N_USERS];
  __shared__ int cv[N_USERS];
  __shared__ float red[256];
  const int k = blockIdx.x, tid = threadIdx.x;
  for (int i = tid; i < N_USERS; i += 256) { sv[i] = s[i]; cv[i] = cid[i]; }
  __syncthreads();
  float m = -3.4e38f;
  for (int i = tid; i < N_USERS; i += 256) if (cv[i] == k) m = fmaxf(m, sv[i]);
  red[tid] = m; __syncthreads();
  for (int st = 128; st; st >>= 1) { if (tid < st) red[tid] = fmaxf(red[tid], red[tid + st]); __syncthreads(); }
  const float smax = red[0];
  __syncthreads();
  float sum = 0.f;
  for (int i = tid; i < N_USERS; i += 256)
    if (cv[i] == k) { float e = __expf(sv[i] - smax); sv[i] = e; sum += e; }
  red[tid] = sum; __syncthreads();
  for (int st = 128; st; st >>= 1) { if (tid < st) red[tid] += red[tid + st]; __syncthreads(); }
  const float den = red[0];
  __syncthreads();
  float a = 0.f;
  for (int i = 0; i < N_USERS; ++i)
    if (cv[i] == k) a += sv[i] * bf2f(hn[(size_t)i * HDIM + tid]);
  rs[(size_t)k * HDIM + tid] = a / den;
}

// ---------- Phase D1: per-head MHA over roles ----------
__global__ __launch_bounds__(256) void k_mha(
    const float* __restrict__ rs,
    const float* __restrict__ Wq, const float* __restrict__ bq,
    const float* __restrict__ Wk, const float* __restrict__ bk,
    const float* __restrict__ Wv, const float* __restrict__ bv,
    float* __restrict__ attout)
{
  __shared__ float q[64][32], kk[64][32], v[64][32];
  __shared__ float att[64][64];
  const int h = blockIdx.x, tid = threadIdx.x;
  for (int idx = tid; idx < 2048; idx += 256) {
    int r = idx >> 5, dd2 = idx & 31;
    int wrow = h * 32 + dd2;
    float aq = bq[wrow], ak = bk[wrow], av = bv[wrow];
    const float* x = rs + (size_t)r * HDIM;
    const float* wq = Wq + (size_t)wrow * HDIM;
    const float* wk = Wk + (size_t)wrow * HDIM;
    const float* wv = Wv + (size_t)wrow * HDIM;
    for (int j = 0; j < HDIM; ++j) {
      float xv = x[j];
      aq += xv * wq[j]; ak += xv * wk[j]; av += xv * wv[j];
    }
    q[r][dd2] = aq; kk[r][dd2] = ak; v[r][dd2] = av;
  }
  __syncthreads();
  for (int idx = tid; idx < 4096; idx += 256) {
    int qr = idx >> 6, kr = idx & 63;
    float sc = 0.f;
    for (int dd2 = 0; dd2 < 32; ++dd2) sc += q[qr][dd2] * kk[kr][dd2];
    att[qr][kr] = sc * 0.17677669529663687f;   // 1/sqrt(32)
  }
  __syncthreads();
  if (tid < 64) {
    float m = -3.4e38f;
    for (int j = 0; j < 64; ++j) m = fmaxf(m, att[tid][j]);
    float sum = 0.f;
    for (int j = 0; j < 64; ++j) { float e = __expf(att[tid][j] - m); att[tid][j] = e; sum += e; }
    float inv = 1.f / sum;
    for (int j = 0; j < 64; ++j) att[tid][j] *= inv;
  }
  __syncthreads();
  for (int idx = tid; idx < 2048; idx += 256) {
    int r = idx >> 5, dd2 = idx & 31;
    float o = 0.f;
    for (int kr = 0; kr < 64; ++kr) o += att[r][kr] * v[kr][dd2];
    attout[(size_t)r * HDIM + h * 32 + dd2] = o;
  }
}

// ---------- Phase D2: mean over roles + Wo projection ----------
__global__ __launch_bounds__(256) void k_out(
    const float* __restrict__ attout, const float* __restrict__ Wo,
    const float* __restrict__ bo, float* __restrict__ out)
{
  __shared__ float m_s[256];
  const int tid = threadIdx.x;
  float mm = 0.f;
  for (int r = 0; r < 64; ++r) mm += attout[(size_t)r * HDIM + tid];
  m_s[tid] = mm * (1.0f / 64.0f);
  __syncthreads();
  float a = bo[tid];
  for (int j = 0; j < HDIM; ++j) a += m_s[j] * Wo[(size_t)tid * HDIM + j];
  out[tid] = a;
}

extern "C" void kernel_launch(void* const* d_in, const int* in_sizes, int n_in,
                              void* d_out, int out_size, void* d_ws, size_t ws_size,
                              hipStream_t stream) {
  const float* hist = (const float*)d_in[0];
  const float* uv   = (const float*)d_in[1];
  const float* cc   = (const float*)d_in[2];
  const float* Wih  = (const float*)d_in[3];
  const float* Whh  = (const float*)d_in[4];
  const float* bih  = (const float*)d_in[5];
  const float* bhh  = (const float*)d_in[6];
  const float* Wq   = (const float*)d_in[7];
  const float* bq   = (const float*)d_in[8];
  const float* Wk   = (const float*)d_in[9];
  const float* bk   = (const float*)d_in[10];
  const float* Wv   = (const float*)d_in[11];
  const float* bv   = (const float*)d_in[12];
  const float* Wo   = (const float*)d_in[13];
  const float* bo   = (const float*)d_in[14];
  const int* lengths = (const int*)d_in[15];
  const int* cid     = (const int*)d_in[16];
  float* out = (float*)d_out;

  unsigned char* ws = (unsigned char*)d_ws;
  unsigned short* hfin  = (unsigned short*)(ws);                      // 2 MB
  unsigned short* hx0   = (unsigned short*)(ws + (2ull << 20));       // 2 MB
  unsigned short* hx1   = (unsigned short*)(ws + (4ull << 20));       // 2 MB
  unsigned int*   ctr   = (unsigned int*)  (ws + (6ull << 20));       // 16 KB
  float* bias   = (float*)(ws + (6ull << 20) + 65536);                // 4 KB
  float* sbuf   = (float*)(ws + (6ull << 20) + 73728);                // 16 KB
  float* rs     = (float*)(ws + (6ull << 20) + 98304);                // 64 KB
  float* attout = (float*)(ws + (6ull << 20) + 163840);               // 64 KB
  unsigned short* wcat  = (unsigned short*)(ws + (8ull << 20));       // 2 MB
  unsigned short* wcatX = (unsigned short*)(ws + (10ull << 20));      // 1.5 MB
  unsigned short* Xbuf  = (unsigned short*)(ws + (16ull << 20));      // 512 MB
  const size_t need = (16ull << 20) + (size_t)N_USERS * T_STEPS * 1024 * 2;
  if (ws_size < need) return;

  hipMemsetAsync(ctr, 0, 16384, stream);

  k_prep<<<1024, 256, 0, stream>>>(Wih, Whh, bih, bhh, wcat, wcatX, bias);
  k_bigx<<<16384, 512, 0, stream>>>(hist, wcatX, Xbuf);
  k_lstm<<<256, 512, 0, stream>>>(Xbuf, hfin, hx0, hx1, wcat, bias, lengths, ctr);

  k_scores<<<1024, 256, 0, stream>>>(uv, cc, cid, sbuf);
  k_role<<<64, 256, 0, stream>>>(sbuf, cid, hfin, rs);
  k_mha<<<8, 256, 0, stream>>>(rs, Wq, bq, Wk, bk, Wv, bv, attout);
  k_out<<<1, 256, 0, stream>>>(attout, Wo, bo, out);
}